// Round 3
// baseline (4351.466 us; speedup 1.0000x reference)
//
#include <hip/hip_runtime.h>

typedef _Float16 half2_t __attribute__((ext_vector_type(2)));
typedef _Float16 half8_t __attribute__((ext_vector_type(8)));

union h8pack { half8_t v; half2_t h2[4]; };

constexpr int BATCH = 512;
constexpr int SEQ   = 1000;
constexpr int HID   = 128;
constexpr int GATES = 4 * HID;   // 512
constexpr int TPB   = 1024;      // 2 threads per gate column (k-split)
constexpr int ROWS  = 2;         // batch rows per block -> 256 blocks = 1/CU
constexpr int KHALF = HID / 2;   // 64 k-elements per thread

#if __has_builtin(__builtin_amdgcn_fdot2)
__device__ __forceinline__ float fdot2(half2_t a, half2_t b, float c) {
  return __builtin_amdgcn_fdot2(a, b, c, false);
}
#else
__device__ __forceinline__ float fdot2(half2_t a, half2_t b, float c) {
  return c + (float)a[0] * (float)b[0] + (float)a[1] * (float)b[1];
}
#endif

__device__ __forceinline__ float fast_sigmoid(float x) {
  x = fminf(fmaxf(x, -30.f), 30.f);
  return __fdividef(1.f, 1.f + __expf(-x));
}
__device__ __forceinline__ float fast_tanh(float x) {
  x = fminf(fmaxf(x, -15.f), 15.f);
  float e = __expf(2.f * x);
  return __fdividef(e - 1.f, e + 1.f);
}

// Load 64 f32 -> 32 half2 registers in 16B chunks; fences every 4 chunks keep
// the transient load window small so init doesn't raise peak pressure.
__device__ __forceinline__ void load_half_row(const float* __restrict__ src,
                                              half2_t* dst) {
  const float4* p = (const float4*)src;
#pragma unroll
  for (int k = 0; k < KHALF / 4; ++k) {   // 16 float4 loads
    float4 f = p[k];
    dst[2 * k]     = half2_t{(_Float16)f.x, (_Float16)f.y};
    dst[2 * k + 1] = half2_t{(_Float16)f.z, (_Float16)f.w};
    if ((k & 3) == 3) asm volatile("" ::: "memory");
  }
}

// amdgpu_waves_per_eu(4,4): EXACTLY 4 waves/EU (one 16-wave block per CU).
// The max bound is the operative part: round-2 showed that a min-only
// constraint (launch_bounds 2nd arg) lets the allocator's occupancy heuristic
// target 8 waves/EU -> 64-VGPR cap -> ~70 regs/thread spilled (73MB scratch
// stores/step in WRITE_SIZE). Capping occupancy at 4 waves/EU unlocks the
// 128-VGPR budget; the ~124-reg working set (96 weight half2 + state) fits.
__global__ __launch_bounds__(TPB)
__attribute__((amdgpu_waves_per_eu(4, 4)))
void lstm_persist(const float* __restrict__ y,
                  const float* __restrict__ W_ih1,
                  const float* __restrict__ W_hh1,
                  const float* __restrict__ b_ih1,
                  const float* __restrict__ b_hh1,
                  const float* __restrict__ W_ih2,
                  const float* __restrict__ W_hh2,
                  const float* __restrict__ b_ih2,
                  const float* __restrict__ b_hh2,
                  const float* __restrict__ W_lin,
                  const float* __restrict__ b_lin,
                  float* __restrict__ out)
{
  const int tid = threadIdx.x;     // 0..1023
  const int j   = tid >> 1;        // gate column 0..511
  const int kh  = tid & 1;         // which half of the k (hidden) dimension
  const int r0  = blockIdx.x * ROWS;

  __shared__ alignas(16) half8_t h1_sh[ROWS][HID / 8];  // h1 state, f16
  __shared__ alignas(16) half8_t h2_sh[ROWS][HID / 8];  // h2 state, f16
  __shared__ float g1_sh[ROWS][GATES];
  __shared__ float g2_sh[ROWS][GATES];
  __shared__ float x_sh[ROWS][SEQ];                     // staged inputs

  // ---- stage x for both rows into LDS (coalesced, one-time) ----
  for (int i = tid; i < ROWS * SEQ; i += TPB) {
    const int r  = (i >= SEQ) ? 1 : 0;
    const int tt = i - r * SEQ;
    x_sh[r][tt] = y[(size_t)(r0 + r) * SEQ + tt];
  }
  // ---- zero the h state ----
  if (tid < 64) {
    half8_t z = {};
    if (tid < 32) ((half8_t*)h1_sh)[tid] = z;
    else          ((half8_t*)h2_sh)[tid - 32] = z;
  }

  // ---- this thread's HALF weight rows, packed f16: 3 x 32 VGPRs ----
  half2_t w1[KHALF / 2], w2[KHALF / 2], w3[KHALF / 2];
  load_half_row(W_hh1 + (size_t)j * HID + kh * KHALF, w1);
  load_half_row(W_ih2 + (size_t)j * HID + kh * KHALF, w2);
  load_half_row(W_hh2 + (size_t)j * HID + kh * KHALF, w3);

  const float wih1  = W_ih1[j];
  const float bias1 = b_ih1[j] + b_hh1[j];
  const float bias2 = b_ih2[j] + b_hh2[j];
  const float wla   = W_lin[tid & 63];
  const float wlb   = W_lin[(tid & 63) + 64];
  const float blin  = b_lin[0];

  float c1v = 0.f;               // layer-1 cell (threads 0..255)
  float c2a = 0.f, c2b = 0.f;    // layer-2 cell (waves 4 and 7, 2 elems each)

  __syncthreads();

  for (int t = 0; t < SEQ; ++t) {
    // ---------- Phase A: layer-1 raw gate partials (all 1024 threads) ----------
    float a0, a1;
    if (kh == 0) {
      a0 = fmaf(x_sh[0][t], wih1, bias1);
      a1 = fmaf(x_sh[1][t], wih1, bias1);
    } else {
      a0 = 0.f; a1 = 0.f;
    }
#pragma unroll
    for (int c = 0; c < 8; ++c) {
      h8pack u0, u1;
      u0.v = h1_sh[0][kh * 8 + c];
      u1.v = h1_sh[1][kh * 8 + c];
#pragma unroll
      for (int q = 0; q < 4; ++q) {
        a0 = fdot2(w1[4 * c + q], u0.h2[q], a0);
        a1 = fdot2(w1[4 * c + q], u1.h2[q], a1);
      }
    }
    a0 += __shfl_xor(a0, 1);     // pair (2j, 2j+1) lives in the same wave
    a1 += __shfl_xor(a1, 1);
    if (kh == 0) { g1_sh[0][j] = a0; g1_sh[1][j] = a1; }
    __syncthreads();   // bar1: g1 ready; h1 safe to overwrite

    // ---------- Phase B: layer-1 cell update (threads 0..255 = waves 0..3) ----------
    if (tid < ROWS * HID) {
      const int r = tid >> 7, jj = tid & (HID - 1);
      float gi = g1_sh[r][jj];
      float gf = g1_sh[r][jj + HID];
      float gg = g1_sh[r][jj + 2 * HID];
      float go = g1_sh[r][jj + 3 * HID];
      float iv = fast_sigmoid(gi);
      float fv = fast_sigmoid(gf);
      float gv = fast_tanh(gg);
      float ov = fast_sigmoid(go);
      c1v = fmaf(fv, c1v, iv * gv);
      ((_Float16*)h1_sh)[tid] = (_Float16)(ov * fast_tanh(c1v));  // flat == tid
    }
    __syncthreads();   // bar2: h1 ready

    // ---------- Phase C: layer-2 raw gate partials (all 1024 threads) ----------
    float s0, s1;
    if (kh == 0) { s0 = bias2; s1 = bias2; }
    else         { s0 = 0.f;   s1 = 0.f; }
#pragma unroll
    for (int c = 0; c < 8; ++c) {          // W_ih2 . h1
      h8pack u0, u1;
      u0.v = h1_sh[0][kh * 8 + c];
      u1.v = h1_sh[1][kh * 8 + c];
#pragma unroll
      for (int q = 0; q < 4; ++q) {
        s0 = fdot2(w2[4 * c + q], u0.h2[q], s0);
        s1 = fdot2(w2[4 * c + q], u1.h2[q], s1);
      }
    }
#pragma unroll
    for (int c = 0; c < 8; ++c) {          // W_hh2 . h2
      h8pack v0, v1;
      v0.v = h2_sh[0][kh * 8 + c];
      v1.v = h2_sh[1][kh * 8 + c];
#pragma unroll
      for (int q = 0; q < 4; ++q) {
        s0 = fdot2(w3[4 * c + q], v0.h2[q], s0);
        s1 = fdot2(w3[4 * c + q], v1.h2[q], s1);
      }
    }
    s0 += __shfl_xor(s0, 1);
    s1 += __shfl_xor(s1, 1);
    if (kh == 0) { g2_sh[0][j] = s0; g2_sh[1][j] = s1; }
    __syncthreads();   // bar3: g2 ready; h2 safe to overwrite

    // ---------- Phase D: layer-2 cell + output (waves 4 and 7, one row each;
    //            overlaps with the other 14 waves starting Phase A of t+1) ----------
    const int wv = tid >> 6;
    if (wv == 4 || wv == 7) {
      const int r = (wv == 4) ? 0 : 1;
      const int l = tid & 63;              // this thread owns elems l and l+64
      float gia = g2_sh[r][l],       gib = g2_sh[r][l + 64];
      float gfa = g2_sh[r][l + 128], gfb = g2_sh[r][l + 192];
      float gga = g2_sh[r][l + 256], ggb = g2_sh[r][l + 320];
      float goa = g2_sh[r][l + 384], gob = g2_sh[r][l + 448];
      float iva = fast_sigmoid(gia), ivb = fast_sigmoid(gib);
      float fva = fast_sigmoid(gfa), fvb = fast_sigmoid(gfb);
      float gva = fast_tanh(gga),    gvb = fast_tanh(ggb);
      float ova = fast_sigmoid(goa), ovb = fast_sigmoid(gob);
      c2a = fmaf(fva, c2a, iva * gva);
      c2b = fmaf(fvb, c2b, ivb * gvb);
      float ha = ova * fast_tanh(c2a);
      float hb = ovb * fast_tanh(c2b);
      _Float16* hp = (_Float16*)h2_sh;
      hp[r * HID + l]      = (_Float16)ha;
      hp[r * HID + l + 64] = (_Float16)hb;
      float pred = fmaf(ha, wla, hb * wlb);
#pragma unroll
      for (int off = 32; off > 0; off >>= 1)
        pred += __shfl_down(pred, off);
      if (l == 0) out[(size_t)(r0 + r) * SEQ + t] = pred + blin;
    }
    // no barrier: next Phase A touches neither g2_sh nor h2_sh; bar1 of t+1
    // (which waves 4/7 reach only after finishing D) orders everything else.
  }
}

extern "C" void kernel_launch(void* const* d_in, const int* in_sizes, int n_in,
                              void* d_out, int out_size, void* d_ws, size_t ws_size,
                              hipStream_t stream) {
  const float* y     = (const float*)d_in[0];
  const float* W_ih1 = (const float*)d_in[1];
  const float* W_hh1 = (const float*)d_in[2];
  const float* b_ih1 = (const float*)d_in[3];
  const float* b_hh1 = (const float*)d_in[4];
  const float* W_ih2 = (const float*)d_in[5];
  const float* W_hh2 = (const float*)d_in[6];
  const float* b_ih2 = (const float*)d_in[7];
  const float* b_hh2 = (const float*)d_in[8];
  const float* W_lin = (const float*)d_in[9];
  const float* b_lin = (const float*)d_in[10];
  float* out = (float*)d_out;

  lstm_persist<<<BATCH / ROWS, TPB, 0, stream>>>(
      y, W_ih1, W_hh1, b_ih1, b_hh1, W_ih2, W_hh2, b_ih2, b_hh2, W_lin, b_lin, out);
}

// Round 4
// 4194.864 us; speedup vs baseline: 1.0373x; 1.0373x over previous
//
#include <hip/hip_runtime.h>

typedef _Float16 half2_t __attribute__((ext_vector_type(2)));
typedef _Float16 half8_t __attribute__((ext_vector_type(8)));

union h8pack { half8_t v; half2_t h2[4]; };

constexpr int BATCH = 512;
constexpr int SEQ   = 1000;
constexpr int HID   = 128;
constexpr int GATES = 4 * HID;   // 512
constexpr int TPB   = 1024;      // 2 threads per gate column (k-split)
constexpr int ROWS  = 2;         // batch rows per block -> 256 blocks = 1/CU
constexpr int KHALF = HID / 2;   // 64 k-elements per thread

#if __has_builtin(__builtin_amdgcn_fdot2)
__device__ __forceinline__ float fdot2(half2_t a, half2_t b, float c) {
  return __builtin_amdgcn_fdot2(a, b, c, false);
}
#else
__device__ __forceinline__ float fdot2(half2_t a, half2_t b, float c) {
  return c + (float)a[0] * (float)b[0] + (float)a[1] * (float)b[1];
}
#endif

__device__ __forceinline__ float fast_sigmoid(float x) {
  x = fminf(fmaxf(x, -30.f), 30.f);
  return __fdividef(1.f, 1.f + __expf(-x));
}
__device__ __forceinline__ float fast_tanh(float x) {
  x = fminf(fmaxf(x, -15.f), 15.f);
  float e = __expf(2.f * x);
  return __fdividef(e - 1.f, e + 1.f);
}

// waves_per_eu(4,4): exactly 4 waves/EU (one 16-wave block per CU) -> 128-VGPR
// budget. CRITICAL: the weight arrays are loaded INLINE with no helper call and
// no asm memory clobbers. Rounds 1-3 passed the array pointers into a helper
// containing asm volatile("":::"memory") fences between the stores; that made
// the stored values conservatively observable -> SROA kept the arrays in
// scratch -> VGPR_Count=64 and a ~23 TB/s scratch-reload stream (VALUBusy 39%,
// first-dispatch WRITE spike 232MB). Round 0's inline pattern allocated fine.
__global__ __launch_bounds__(TPB)
__attribute__((amdgpu_waves_per_eu(4, 4)))
void lstm_persist(const float* __restrict__ y,
                  const float* __restrict__ W_ih1,
                  const float* __restrict__ W_hh1,
                  const float* __restrict__ b_ih1,
                  const float* __restrict__ b_hh1,
                  const float* __restrict__ W_ih2,
                  const float* __restrict__ W_hh2,
                  const float* __restrict__ b_ih2,
                  const float* __restrict__ b_hh2,
                  const float* __restrict__ W_lin,
                  const float* __restrict__ b_lin,
                  float* __restrict__ out)
{
  const int tid = threadIdx.x;     // 0..1023
  const int j   = tid >> 1;        // gate column 0..511
  const int kh  = tid & 1;         // which half of the k (hidden) dimension
  const int r0  = blockIdx.x * ROWS;

  __shared__ alignas(16) half8_t h1_sh[ROWS][HID / 8];  // h1 state, f16
  __shared__ alignas(16) half8_t h2_sh[ROWS][HID / 8];  // h2 state, f16
  __shared__ float g1_sh[ROWS][GATES];
  __shared__ float g2_sh[ROWS][GATES];
  __shared__ float x_sh[ROWS][SEQ];                     // staged inputs

  // ---- stage x for both rows into LDS (coalesced, one-time) ----
  for (int i = tid; i < ROWS * SEQ; i += TPB) {
    const int r  = (i >= SEQ) ? 1 : 0;
    const int tt = i - r * SEQ;
    x_sh[r][tt] = y[(size_t)(r0 + r) * SEQ + tt];
  }
  // ---- zero the h state ----
  if (tid < 64) {
    half8_t z = {};
    if (tid < 32) ((half8_t*)h1_sh)[tid] = z;
    else          ((half8_t*)h2_sh)[tid - 32] = z;
  }

  // ---- this thread's HALF weight rows, packed f16: 3 x 32 VGPRs ----
  // Inline, fully unrolled, constant indices only (promotable to registers).
  half2_t w1[KHALF / 2], w2[KHALF / 2], w3[KHALF / 2];
  {
    const float2* p1 = (const float2*)(W_hh1 + (size_t)j * HID + kh * KHALF);
    const float2* p2 = (const float2*)(W_ih2 + (size_t)j * HID + kh * KHALF);
    const float2* p3 = (const float2*)(W_hh2 + (size_t)j * HID + kh * KHALF);
#pragma unroll
    for (int k = 0; k < KHALF / 2; ++k) {
      float2 a  = p1[k]; w1[k] = half2_t{(_Float16)a.x,  (_Float16)a.y};
      float2 bb = p2[k]; w2[k] = half2_t{(_Float16)bb.x, (_Float16)bb.y};
      float2 cc = p3[k]; w3[k] = half2_t{(_Float16)cc.x, (_Float16)cc.y};
    }
  }

  const float wih1  = W_ih1[j];
  const float bias1 = b_ih1[j] + b_hh1[j];
  const float bias2 = b_ih2[j] + b_hh2[j];
  const float wla   = W_lin[tid & 63];
  const float wlb   = W_lin[(tid & 63) + 64];
  const float blin  = b_lin[0];

  float c1v = 0.f;               // layer-1 cell (threads 0..255)
  float c2a = 0.f, c2b = 0.f;    // layer-2 cell (waves 4 and 7, 2 elems each)

  __syncthreads();

  for (int t = 0; t < SEQ; ++t) {
    // ---------- Phase A: layer-1 raw gate partials (all 1024 threads) ----------
    float a0, a1;
    if (kh == 0) {
      a0 = fmaf(x_sh[0][t], wih1, bias1);
      a1 = fmaf(x_sh[1][t], wih1, bias1);
    } else {
      a0 = 0.f; a1 = 0.f;
    }
#pragma unroll
    for (int c = 0; c < 8; ++c) {
      h8pack u0, u1;
      u0.v = h1_sh[0][kh * 8 + c];
      u1.v = h1_sh[1][kh * 8 + c];
#pragma unroll
      for (int q = 0; q < 4; ++q) {
        a0 = fdot2(w1[4 * c + q], u0.h2[q], a0);
        a1 = fdot2(w1[4 * c + q], u1.h2[q], a1);
      }
    }
    a0 += __shfl_xor(a0, 1);     // pair (2j, 2j+1) lives in the same wave
    a1 += __shfl_xor(a1, 1);
    if (kh == 0) { g1_sh[0][j] = a0; g1_sh[1][j] = a1; }
    __syncthreads();   // bar1: g1 ready; h1 safe to overwrite

    // ---------- Phase B: layer-1 cell update (threads 0..255 = waves 0..3) ----------
    if (tid < ROWS * HID) {
      const int r = tid >> 7, jj = tid & (HID - 1);
      float gi = g1_sh[r][jj];
      float gf = g1_sh[r][jj + HID];
      float gg = g1_sh[r][jj + 2 * HID];
      float go = g1_sh[r][jj + 3 * HID];
      float iv = fast_sigmoid(gi);
      float fv = fast_sigmoid(gf);
      float gv = fast_tanh(gg);
      float ov = fast_sigmoid(go);
      c1v = fmaf(fv, c1v, iv * gv);
      ((_Float16*)h1_sh)[tid] = (_Float16)(ov * fast_tanh(c1v));  // flat == tid
    }
    __syncthreads();   // bar2: h1 ready

    // ---------- Phase C: layer-2 raw gate partials (all 1024 threads) ----------
    float s0, s1;
    if (kh == 0) { s0 = bias2; s1 = bias2; }
    else         { s0 = 0.f;   s1 = 0.f; }
#pragma unroll
    for (int c = 0; c < 8; ++c) {          // W_ih2 . h1
      h8pack u0, u1;
      u0.v = h1_sh[0][kh * 8 + c];
      u1.v = h1_sh[1][kh * 8 + c];
#pragma unroll
      for (int q = 0; q < 4; ++q) {
        s0 = fdot2(w2[4 * c + q], u0.h2[q], s0);
        s1 = fdot2(w2[4 * c + q], u1.h2[q], s1);
      }
    }
#pragma unroll
    for (int c = 0; c < 8; ++c) {          // W_hh2 . h2
      h8pack v0, v1;
      v0.v = h2_sh[0][kh * 8 + c];
      v1.v = h2_sh[1][kh * 8 + c];
#pragma unroll
      for (int q = 0; q < 4; ++q) {
        s0 = fdot2(w3[4 * c + q], v0.h2[q], s0);
        s1 = fdot2(w3[4 * c + q], v1.h2[q], s1);
      }
    }
    s0 += __shfl_xor(s0, 1);
    s1 += __shfl_xor(s1, 1);
    if (kh == 0) { g2_sh[0][j] = s0; g2_sh[1][j] = s1; }
    __syncthreads();   // bar3: g2 ready; h2 safe to overwrite

    // ---------- Phase D: layer-2 cell + output (waves 4 and 7, one row each;
    //            overlaps with the other 14 waves starting Phase A of t+1) ----------
    const int wv = tid >> 6;
    if (wv == 4 || wv == 7) {
      const int r = (wv == 4) ? 0 : 1;
      const int l = tid & 63;              // this thread owns elems l and l+64
      float gia = g2_sh[r][l],       gib = g2_sh[r][l + 64];
      float gfa = g2_sh[r][l + 128], gfb = g2_sh[r][l + 192];
      float gga = g2_sh[r][l + 256], ggb = g2_sh[r][l + 320];
      float goa = g2_sh[r][l + 384], gob = g2_sh[r][l + 448];
      float iva = fast_sigmoid(gia), ivb = fast_sigmoid(gib);
      float fva = fast_sigmoid(gfa), fvb = fast_sigmoid(gfb);
      float gva = fast_tanh(gga),    gvb = fast_tanh(ggb);
      float ova = fast_sigmoid(goa), ovb = fast_sigmoid(gob);
      c2a = fmaf(fva, c2a, iva * gva);
      c2b = fmaf(fvb, c2b, ivb * gvb);
      float ha = ova * fast_tanh(c2a);
      float hb = ovb * fast_tanh(c2b);
      _Float16* hp = (_Float16*)h2_sh;
      hp[r * HID + l]      = (_Float16)ha;
      hp[r * HID + l + 64] = (_Float16)hb;
      float pred = fmaf(ha, wla, hb * wlb);
#pragma unroll
      for (int off = 32; off > 0; off >>= 1)
        pred += __shfl_down(pred, off);
      if (l == 0) out[(size_t)(r0 + r) * SEQ + t] = pred + blin;
    }
    // no barrier: next Phase A touches neither g2_sh nor h2_sh; bar1 of t+1
    // (which waves 4/7 reach only after finishing D) orders everything else.
  }
}

extern "C" void kernel_launch(void* const* d_in, const int* in_sizes, int n_in,
                              void* d_out, int out_size, void* d_ws, size_t ws_size,
                              hipStream_t stream) {
  const float* y     = (const float*)d_in[0];
  const float* W_ih1 = (const float*)d_in[1];
  const float* W_hh1 = (const float*)d_in[2];
  const float* b_ih1 = (const float*)d_in[3];
  const float* b_hh1 = (const float*)d_in[4];
  const float* W_ih2 = (const float*)d_in[5];
  const float* W_hh2 = (const float*)d_in[6];
  const float* b_ih2 = (const float*)d_in[7];
  const float* b_hh2 = (const float*)d_in[8];
  const float* W_lin = (const float*)d_in[9];
  const float* b_lin = (const float*)d_in[10];
  float* out = (float*)d_out;

  lstm_persist<<<BATCH / ROWS, TPB, 0, stream>>>(
      y, W_ih1, W_hh1, b_ih1, b_hh1, W_ih2, W_hh2, b_ih2, b_hh2, W_lin, b_lin, out);
}

// Round 5
// 3182.734 us; speedup vs baseline: 1.3672x; 1.3180x over previous
//
#include <hip/hip_runtime.h>

typedef _Float16 half2_t __attribute__((ext_vector_type(2)));
typedef _Float16 half8_t __attribute__((ext_vector_type(8)));

union h8pack { half8_t v; half2_t h2[4]; };

constexpr int BATCH = 512;
constexpr int SEQ   = 1000;
constexpr int HID   = 128;
constexpr int GATES = 4 * HID;   // 512
constexpr int TPB   = 1024;      // 2 threads per gate column (k-split)
constexpr int ROWS  = 2;         // batch rows per block -> 256 blocks = 1/CU
constexpr int KHALF = HID / 2;   // 64 k-elements per thread

#if __has_builtin(__builtin_amdgcn_fdot2)
__device__ __forceinline__ float fdot2(half2_t a, half2_t b, float c) {
  return __builtin_amdgcn_fdot2(a, b, c, false);
}
#else
__device__ __forceinline__ float fdot2(half2_t a, half2_t b, float c) {
  return c + (float)a[0] * (float)b[0] + (float)a[1] * (float)b[1];
}
#endif

__device__ __forceinline__ float fast_sigmoid(float x) {
  x = fminf(fmaxf(x, -30.f), 30.f);
  return __fdividef(1.f, 1.f + __expf(-x));
}
__device__ __forceinline__ float fast_tanh(float x) {
  x = fminf(fmaxf(x, -15.f), 15.f);
  float e = __expf(2.f * x);
  return __fdividef(e - 1.f, e + 1.f);
}

// 4 fdot2 of one half8 against one h8pack
#define DOT8(acc, W, U) { h8pack _w; _w.v = (W);            \
    acc = fdot2(_w.h2[0], (U).h2[0], acc);                  \
    acc = fdot2(_w.h2[1], (U).h2[1], acc);                  \
    acc = fdot2(_w.h2[2], (U).h2[2], acc);                  \
    acc = fdot2(_w.h2[3], (U).h2[3], acc); }

// load 8 consecutive f32 and pack to one half8 register
#define LDW(dst, p, q) { float4 _f0 = (p)[2*(q)]; float4 _f1 = (p)[2*(q)+1]; \
    dst = half8_t{(_Float16)_f0.x, (_Float16)_f0.y, (_Float16)_f0.z,         \
                  (_Float16)_f0.w, (_Float16)_f1.x, (_Float16)_f1.y,         \
                  (_Float16)_f1.z, (_Float16)_f1.w}; }

// Register-budget history: TPB=1024 kernels get a 64-VGPR budget from the
// allocator's 8-waves/EU target no matter what launch_bounds/waves_per_eu says
// (rounds 1-4: VGPR_Count=64, weight arrays spilled, VALUBusy ~40%).
// Countermeasures here: (a) W_hh2 lives in LDS (128KB, bank-friendly
// transposed layout) so register weights drop 96->64; (b) weights are 16
// NAMED half8 variables, never arrays -> promotion structurally guaranteed;
// (c) 148KB LDS forces 1 block/CU, pushing the compiler's implied occupancy
// (input to the VGPR budget) to 4 waves/EU; (d) wpe(4,8) min-only hint.
__global__ __launch_bounds__(TPB)
__attribute__((amdgpu_waves_per_eu(4, 8)))
void lstm_persist(const float* __restrict__ y,
                  const float* __restrict__ W_ih1,
                  const float* __restrict__ W_hh1,
                  const float* __restrict__ b_ih1,
                  const float* __restrict__ b_hh1,
                  const float* __restrict__ W_ih2,
                  const float* __restrict__ W_hh2,
                  const float* __restrict__ b_ih2,
                  const float* __restrict__ b_hh2,
                  const float* __restrict__ W_lin,
                  const float* __restrict__ b_lin,
                  float* __restrict__ out)
{
  const int tid = threadIdx.x;     // 0..1023
  const int j   = tid >> 1;        // gate column 0..511
  const int kh  = tid & 1;         // which half of the k (hidden) dimension
  const int kh8 = kh * 8;
  const int r0  = blockIdx.x * ROWS;

  __shared__ alignas(16) half8_t h1_sh[ROWS][HID / 8];  // h1 state, f16
  __shared__ alignas(16) half8_t h2_sh[ROWS][HID / 8];  // h2 state, f16
  __shared__ float g1_sh[ROWS][GATES];
  __shared__ float g2_sh[ROWS][GATES];
  __shared__ float x_sh[ROWS][SEQ];                     // staged inputs
  // W_hh2, f16, transposed: slot (kq*512 + row) holds W_hh2[row][kq*8..kq*8+7].
  // Wave read at fixed (kh,q): 32 consecutive rows, 16B stride -> all banks,
  // lane-pairs (kh=0/1) 2-way on same bank = free.
  __shared__ half8_t w3_lds[16 * 512];                  // 128 KiB

  // ---- stage x for both rows into LDS (coalesced, one-time) ----
  for (int i = tid; i < ROWS * SEQ; i += TPB) {
    const int r  = (i >= SEQ) ? 1 : 0;
    const int tt = i - r * SEQ;
    x_sh[r][tt] = y[(size_t)(r0 + r) * SEQ + tt];
  }
  // ---- zero the h state ----
  if (tid < 64) {
    half8_t z = {};
    if (tid < 32) ((half8_t*)h1_sh)[tid] = z;
    else          ((half8_t*)h2_sh)[tid - 32] = z;
  }
  // ---- stage W_hh2 into LDS (coalesced global reads, one-time) ----
  for (int s = tid; s < 16 * 512; s += TPB) {   // 8 iters
    const int row = s >> 4, kq = s & 15;
    const float4* g = (const float4*)(W_hh2 + (size_t)row * HID + kq * 8);
    float4 f0 = g[0], f1 = g[1];
    w3_lds[kq * 512 + row] =
        half8_t{(_Float16)f0.x, (_Float16)f0.y, (_Float16)f0.z, (_Float16)f0.w,
                (_Float16)f1.x, (_Float16)f1.y, (_Float16)f1.z, (_Float16)f1.w};
  }

  // ---- register weights: 16 NAMED half8 (64 VGPRs), no arrays ----
  half8_t W10, W11, W12, W13, W14, W15, W16, W17;   // W_hh1 row slice
  half8_t W20, W21, W22, W23, W24, W25, W26, W27;   // W_ih2 row slice
  {
    const float4* p1 = (const float4*)(W_hh1 + (size_t)j * HID + kh * KHALF);
    const float4* p2 = (const float4*)(W_ih2 + (size_t)j * HID + kh * KHALF);
    LDW(W10, p1, 0) LDW(W11, p1, 1) LDW(W12, p1, 2) LDW(W13, p1, 3)
    LDW(W14, p1, 4) LDW(W15, p1, 5) LDW(W16, p1, 6) LDW(W17, p1, 7)
    LDW(W20, p2, 0) LDW(W21, p2, 1) LDW(W22, p2, 2) LDW(W23, p2, 3)
    LDW(W24, p2, 4) LDW(W25, p2, 5) LDW(W26, p2, 6) LDW(W27, p2, 7)
  }

  const float wih1  = W_ih1[j];
  const float bias1 = b_ih1[j] + b_hh1[j];
  const float bias2 = b_ih2[j] + b_hh2[j];
  const float wla   = W_lin[tid & 63];
  const float wlb   = W_lin[(tid & 63) + 64];
  const float blin  = b_lin[0];

  float c1v = 0.f;               // layer-1 cell (threads 0..255)
  float c2a = 0.f, c2b = 0.f;    // layer-2 cell (waves 4 and 7, 2 elems each)

  __syncthreads();

  for (int t = 0; t < SEQ; ++t) {
    // ---------- Phase A: layer-1 raw gate partials (all 1024 threads) ----------
    float a0, a1;
    if (kh == 0) {
      a0 = fmaf(x_sh[0][t], wih1, bias1);
      a1 = fmaf(x_sh[1][t], wih1, bias1);
    } else {
      a0 = 0.f; a1 = 0.f;
    }
#define PHA(c, W) { h8pack u0, u1;                   \
      u0.v = h1_sh[0][kh8 + c];                      \
      u1.v = h1_sh[1][kh8 + c];                      \
      DOT8(a0, W, u0); DOT8(a1, W, u1); }
    PHA(0, W10) PHA(1, W11) PHA(2, W12) PHA(3, W13)
    PHA(4, W14) PHA(5, W15) PHA(6, W16) PHA(7, W17)
#undef PHA
    a0 += __shfl_xor(a0, 1);     // pair (2j, 2j+1) lives in the same wave
    a1 += __shfl_xor(a1, 1);
    if (kh == 0) { g1_sh[0][j] = a0; g1_sh[1][j] = a1; }
    __syncthreads();   // bar1: g1 ready; h1 safe to overwrite

    // ---------- Phase B: layer-1 cell update (threads 0..255 = waves 0..3) ----------
    if (tid < ROWS * HID) {
      const int r = tid >> 7, jj = tid & (HID - 1);
      float gi = g1_sh[r][jj];
      float gf = g1_sh[r][jj + HID];
      float gg = g1_sh[r][jj + 2 * HID];
      float go = g1_sh[r][jj + 3 * HID];
      float iv = fast_sigmoid(gi);
      float fv = fast_sigmoid(gf);
      float gv = fast_tanh(gg);
      float ov = fast_sigmoid(go);
      c1v = fmaf(fv, c1v, iv * gv);
      ((_Float16*)h1_sh)[tid] = (_Float16)(ov * fast_tanh(c1v));  // flat == tid
    }
    __syncthreads();   // bar2: h1 ready

    // ---------- Phase C: layer-2 raw gate partials (all 1024 threads) ----------
    float s0, s1;
    if (kh == 0) { s0 = bias2; s1 = bias2; }
    else         { s0 = 0.f;   s1 = 0.f; }
#define PHC1(c, W) { h8pack u0, u1;                  \
      u0.v = h1_sh[0][kh8 + c];                      \
      u1.v = h1_sh[1][kh8 + c];                      \
      DOT8(s0, W, u0); DOT8(s1, W, u1); }
    PHC1(0, W20) PHC1(1, W21) PHC1(2, W22) PHC1(3, W23)
    PHC1(4, W24) PHC1(5, W25) PHC1(6, W26) PHC1(7, W27)
#undef PHC1
#define PHC2(c) { h8pack v0, v1;                     \
      half8_t wr = w3_lds[(kh8 + c) * 512 + j];      \
      v0.v = h2_sh[0][kh8 + c];                      \
      v1.v = h2_sh[1][kh8 + c];                      \
      DOT8(s0, wr, v0); DOT8(s1, wr, v1); }
    PHC2(0) PHC2(1) PHC2(2) PHC2(3)
    PHC2(4) PHC2(5) PHC2(6) PHC2(7)
#undef PHC2
    s0 += __shfl_xor(s0, 1);
    s1 += __shfl_xor(s1, 1);
    if (kh == 0) { g2_sh[0][j] = s0; g2_sh[1][j] = s1; }
    __syncthreads();   // bar3: g2 ready; h2 safe to overwrite

    // ---------- Phase D: layer-2 cell + output (waves 4 and 7, one row each;
    //            overlaps with the other 14 waves starting Phase A of t+1) ----------
    const int wv = tid >> 6;
    if (wv == 4 || wv == 7) {
      const int r = (wv == 4) ? 0 : 1;
      const int l = tid & 63;              // this thread owns elems l and l+64
      float gia = g2_sh[r][l],       gib = g2_sh[r][l + 64];
      float gfa = g2_sh[r][l + 128], gfb = g2_sh[r][l + 192];
      float gga = g2_sh[r][l + 256], ggb = g2_sh[r][l + 320];
      float goa = g2_sh[r][l + 384], gob = g2_sh[r][l + 448];
      float iva = fast_sigmoid(gia), ivb = fast_sigmoid(gib);
      float fva = fast_sigmoid(gfa), fvb = fast_sigmoid(gfb);
      float gva = fast_tanh(gga),    gvb = fast_tanh(ggb);
      float ova = fast_sigmoid(goa), ovb = fast_sigmoid(gob);
      c2a = fmaf(fva, c2a, iva * gva);
      c2b = fmaf(fvb, c2b, ivb * gvb);
      float ha = ova * fast_tanh(c2a);
      float hb = ovb * fast_tanh(c2b);
      _Float16* hp = (_Float16*)h2_sh;
      hp[r * HID + l]      = (_Float16)ha;
      hp[r * HID + l + 64] = (_Float16)hb;
      float pred = fmaf(ha, wla, hb * wlb);
#pragma unroll
      for (int off = 32; off > 0; off >>= 1)
        pred += __shfl_down(pred, off);
      if (l == 0) out[(size_t)(r0 + r) * SEQ + t] = pred + blin;
    }
    // no barrier: next Phase A touches neither g2_sh nor h2_sh; bar1 of t+1
    // (which waves 4/7 reach only after finishing D) orders everything else.
  }
}

extern "C" void kernel_launch(void* const* d_in, const int* in_sizes, int n_in,
                              void* d_out, int out_size, void* d_ws, size_t ws_size,
                              hipStream_t stream) {
  const float* y     = (const float*)d_in[0];
  const float* W_ih1 = (const float*)d_in[1];
  const float* W_hh1 = (const float*)d_in[2];
  const float* b_ih1 = (const float*)d_in[3];
  const float* b_hh1 = (const float*)d_in[4];
  const float* W_ih2 = (const float*)d_in[5];
  const float* W_hh2 = (const float*)d_in[6];
  const float* b_ih2 = (const float*)d_in[7];
  const float* b_hh2 = (const float*)d_in[8];
  const float* W_lin = (const float*)d_in[9];
  const float* b_lin = (const float*)d_in[10];
  float* out = (float*)d_out;

  lstm_persist<<<BATCH / ROWS, TPB, 0, stream>>>(
      y, W_ih1, W_hh1, b_ih1, b_hh1, W_ih2, W_hh2, b_ih2, b_hh2, W_lin, b_lin, out);
}

// Round 6
// 3162.773 us; speedup vs baseline: 1.3758x; 1.0063x over previous
//
#include <hip/hip_runtime.h>

typedef _Float16 half2_t __attribute__((ext_vector_type(2)));
typedef _Float16 half8_t __attribute__((ext_vector_type(8)));

union h8pack { half8_t v; half2_t h2[4]; };

constexpr int BATCH = 512;
constexpr int SEQ   = 1000;
constexpr int HID   = 128;
constexpr int GATES = 4 * HID;   // 512
constexpr int TPB   = 1024;      // 2 threads per gate column (k-split)
constexpr int ROWS  = 2;         // batch rows per block -> 256 blocks = 1/CU
constexpr int KHALF = HID / 2;   // 64 k-elements per thread

#if __has_builtin(__builtin_amdgcn_fdot2)
__device__ __forceinline__ float fdot2(half2_t a, half2_t b, float c) {
  return __builtin_amdgcn_fdot2(a, b, c, false);
}
#else
__device__ __forceinline__ float fdot2(half2_t a, half2_t b, float c) {
  return c + (float)a[0] * (float)b[0] + (float)a[1] * (float)b[1];
}
#endif

__device__ __forceinline__ float fast_sigmoid(float x) {
  x = fminf(fmaxf(x, -30.f), 30.f);
  return __fdividef(1.f, 1.f + __expf(-x));
}
__device__ __forceinline__ float fast_tanh(float x) {
  x = fminf(fmaxf(x, -15.f), 15.f);
  float e = __expf(2.f * x);
  return __fdividef(e - 1.f, e + 1.f);
}

// 4 fdot2 of one half8 against one h8pack
#define DOT8(acc, W, U) { h8pack _w; _w.v = (W);            \
    acc = fdot2(_w.h2[0], (U).h2[0], acc);                  \
    acc = fdot2(_w.h2[1], (U).h2[1], acc);                  \
    acc = fdot2(_w.h2[2], (U).h2[2], acc);                  \
    acc = fdot2(_w.h2[3], (U).h2[3], acc); }

// load 8 consecutive f32 and pack to one half8 register
#define LDW(dst, p, q) { float4 _f0 = (p)[2*(q)]; float4 _f1 = (p)[2*(q)+1]; \
    dst = half8_t{(_Float16)_f0.x, (_Float16)_f0.y, (_Float16)_f0.z,         \
                  (_Float16)_f0.w, (_Float16)_f1.x, (_Float16)_f1.y,         \
                  (_Float16)_f1.z, (_Float16)_f1.w}; }

// w3_lds granule map: slot for (kq, row j). The kh*4-granule (64B) rotation
// puts kh=0 lanes on banks 0..15 and kh=1 lanes on banks 16..31 within each
// 8-lane phase of the PHC2 ds_read_b128 -> all 32 banks covered exactly once
// (round-5 counter: 1.33e8 SQ_LDS_BANK_CONFLICT from the unrotated layout,
// where the +65536B kh offset was bank-neutral: 65536/4 % 32 == 0).
#define W3IDX(kq, j) ((kq) * 512 + ((((j) + (((kq) >> 3) << 2))) & 511))

// Register-budget history: at TPB=1024 the occupancy-derived VGPR budget has
// been pinned at 64 through rounds 1-5 regardless of launch_bounds /
// waves_per_eu; round 5 showed the 64-reg allocator rematerializes the weight
// set (reload+cvt per use -> ~5x VALU inflation, VALUBusy 54% at 8430 cyc per
// step). amdgpu_num_vgpr(128) pins the allocation limit DIRECTLY at the
// backend (not via the occupancy heuristic). 128 regs @ 16 waves/CU is
// exactly the hardware cap (512 VGPR/EU / 4 waves) and the ~95-reg need fits.
__global__ __launch_bounds__(TPB)
__attribute__((amdgpu_waves_per_eu(4, 4)))
#if __has_attribute(amdgpu_num_vgpr)
__attribute__((amdgpu_num_vgpr(128)))
#endif
void lstm_persist(const float* __restrict__ y,
                  const float* __restrict__ W_ih1,
                  const float* __restrict__ W_hh1,
                  const float* __restrict__ b_ih1,
                  const float* __restrict__ b_hh1,
                  const float* __restrict__ W_ih2,
                  const float* __restrict__ W_hh2,
                  const float* __restrict__ b_ih2,
                  const float* __restrict__ b_hh2,
                  const float* __restrict__ W_lin,
                  const float* __restrict__ b_lin,
                  float* __restrict__ out)
{
  const int tid = threadIdx.x;     // 0..1023
  const int j   = tid >> 1;        // gate column 0..511
  const int kh  = tid & 1;         // which half of the k (hidden) dimension
  const int kh8 = kh * 8;
  const int r0  = blockIdx.x * ROWS;

  __shared__ alignas(16) half8_t h1_sh[ROWS][HID / 8];  // h1 state, f16
  __shared__ alignas(16) half8_t h2_sh[ROWS][HID / 8];  // h2 state, f16
  __shared__ float g1_sh[ROWS][GATES];
  __shared__ float g2_sh[ROWS][GATES];
  __shared__ float x_sh[ROWS][SEQ];                     // staged inputs
  __shared__ half8_t w3_lds[16 * 512];                  // W_hh2 f16, 128 KiB

  // ---- stage x for both rows into LDS (coalesced, one-time) ----
  for (int i = tid; i < ROWS * SEQ; i += TPB) {
    const int r  = (i >= SEQ) ? 1 : 0;
    const int tt = i - r * SEQ;
    x_sh[r][tt] = y[(size_t)(r0 + r) * SEQ + tt];
  }
  // ---- zero the h state ----
  if (tid < 64) {
    half8_t z = {};
    if (tid < 32) ((half8_t*)h1_sh)[tid] = z;
    else          ((half8_t*)h2_sh)[tid - 32] = z;
  }
  // ---- stage W_hh2 into LDS (coalesced global reads, one-time) ----
  for (int s = tid; s < 16 * 512; s += TPB) {   // 8 iters
    const int row = s >> 4, kq = s & 15;
    const float4* g = (const float4*)(W_hh2 + (size_t)row * HID + kq * 8);
    float4 f0 = g[0], f1 = g[1];
    w3_lds[W3IDX(kq, row)] =
        half8_t{(_Float16)f0.x, (_Float16)f0.y, (_Float16)f0.z, (_Float16)f0.w,
                (_Float16)f1.x, (_Float16)f1.y, (_Float16)f1.z, (_Float16)f1.w};
  }

  // ---- register weights: 16 NAMED half8 (64 VGPRs), no arrays ----
  half8_t W10, W11, W12, W13, W14, W15, W16, W17;   // W_hh1 row slice
  half8_t W20, W21, W22, W23, W24, W25, W26, W27;   // W_ih2 row slice
  {
    const float4* p1 = (const float4*)(W_hh1 + (size_t)j * HID + kh * KHALF);
    const float4* p2 = (const float4*)(W_ih2 + (size_t)j * HID + kh * KHALF);
    LDW(W10, p1, 0) LDW(W11, p1, 1) LDW(W12, p1, 2) LDW(W13, p1, 3)
    LDW(W14, p1, 4) LDW(W15, p1, 5) LDW(W16, p1, 6) LDW(W17, p1, 7)
    LDW(W20, p2, 0) LDW(W21, p2, 1) LDW(W22, p2, 2) LDW(W23, p2, 3)
    LDW(W24, p2, 4) LDW(W25, p2, 5) LDW(W26, p2, 6) LDW(W27, p2, 7)
  }

  const float wih1  = W_ih1[j];
  const float bias1 = b_ih1[j] + b_hh1[j];
  const float bias2 = b_ih2[j] + b_hh2[j];
  const float wla   = W_lin[tid & 63];
  const float wlb   = W_lin[(tid & 63) + 64];
  const float blin  = b_lin[0];

  float c1v = 0.f;               // layer-1 cell (threads 0..255)
  float c2a = 0.f, c2b = 0.f;    // layer-2 cell (waves 4 and 7, 2 elems each)

  __syncthreads();

  for (int t = 0; t < SEQ; ++t) {
    // ---------- Phase A: layer-1 raw gate partials (all 1024 threads) ----------
    float a0, a1;
    if (kh == 0) {
      a0 = fmaf(x_sh[0][t], wih1, bias1);
      a1 = fmaf(x_sh[1][t], wih1, bias1);
    } else {
      a0 = 0.f; a1 = 0.f;
    }
#define PHA(c, W) { h8pack u0, u1;                   \
      u0.v = h1_sh[0][kh8 + c];                      \
      u1.v = h1_sh[1][kh8 + c];                      \
      DOT8(a0, W, u0); DOT8(a1, W, u1); }
    PHA(0, W10) PHA(1, W11) PHA(2, W12) PHA(3, W13)
    PHA(4, W14) PHA(5, W15) PHA(6, W16) PHA(7, W17)
#undef PHA
    a0 += __shfl_xor(a0, 1);     // pair (2j, 2j+1) lives in the same wave
    a1 += __shfl_xor(a1, 1);
    if (kh == 0) { g1_sh[0][j] = a0; g1_sh[1][j] = a1; }
    __syncthreads();   // bar1: g1 ready; h1 safe to overwrite

    // ---------- Phase B: layer-1 cell update (threads 0..255 = waves 0..3) ----------
    if (tid < ROWS * HID) {
      const int r = tid >> 7, jj = tid & (HID - 1);
      float gi = g1_sh[r][jj];
      float gf = g1_sh[r][jj + HID];
      float gg = g1_sh[r][jj + 2 * HID];
      float go = g1_sh[r][jj + 3 * HID];
      float iv = fast_sigmoid(gi);
      float fv = fast_sigmoid(gf);
      float gv = fast_tanh(gg);
      float ov = fast_sigmoid(go);
      c1v = fmaf(fv, c1v, iv * gv);
      ((_Float16*)h1_sh)[tid] = (_Float16)(ov * fast_tanh(c1v));  // flat == tid
    }
    __syncthreads();   // bar2: h1 ready

    // ---------- Phase C: layer-2 raw gate partials (all 1024 threads) ----------
    float s0, s1;
    if (kh == 0) { s0 = bias2; s1 = bias2; }
    else         { s0 = 0.f;   s1 = 0.f; }
#define PHC1(c, W) { h8pack u0, u1;                  \
      u0.v = h1_sh[0][kh8 + c];                      \
      u1.v = h1_sh[1][kh8 + c];                      \
      DOT8(s0, W, u0); DOT8(s1, W, u1); }
    PHC1(0, W20) PHC1(1, W21) PHC1(2, W22) PHC1(3, W23)
    PHC1(4, W24) PHC1(5, W25) PHC1(6, W26) PHC1(7, W27)
#undef PHC1
#define PHC2(c) { h8pack v0, v1;                     \
      half8_t wr = w3_lds[W3IDX(kh8 + c, j)];        \
      v0.v = h2_sh[0][kh8 + c];                      \
      v1.v = h2_sh[1][kh8 + c];                      \
      DOT8(s0, wr, v0); DOT8(s1, wr, v1); }
    PHC2(0) PHC2(1) PHC2(2) PHC2(3)
    PHC2(4) PHC2(5) PHC2(6) PHC2(7)
#undef PHC2
    s0 += __shfl_xor(s0, 1);
    s1 += __shfl_xor(s1, 1);
    if (kh == 0) { g2_sh[0][j] = s0; g2_sh[1][j] = s1; }
    __syncthreads();   // bar3: g2 ready; h2 safe to overwrite

    // ---------- Phase D: layer-2 cell + output (waves 4 and 7, one row each;
    //            overlaps with the other 14 waves starting Phase A of t+1) ----------
    const int wv = tid >> 6;
    if (wv == 4 || wv == 7) {
      const int r = (wv == 4) ? 0 : 1;
      const int l = tid & 63;              // this thread owns elems l and l+64
      float gia = g2_sh[r][l],       gib = g2_sh[r][l + 64];
      float gfa = g2_sh[r][l + 128], gfb = g2_sh[r][l + 192];
      float gga = g2_sh[r][l + 256], ggb = g2_sh[r][l + 320];
      float goa = g2_sh[r][l + 384], gob = g2_sh[r][l + 448];
      float iva = fast_sigmoid(gia), ivb = fast_sigmoid(gib);
      float fva = fast_sigmoid(gfa), fvb = fast_sigmoid(gfb);
      float gva = fast_tanh(gga),    gvb = fast_tanh(ggb);
      float ova = fast_sigmoid(goa), ovb = fast_sigmoid(gob);
      c2a = fmaf(fva, c2a, iva * gva);
      c2b = fmaf(fvb, c2b, ivb * gvb);
      float ha = ova * fast_tanh(c2a);
      float hb = ovb * fast_tanh(c2b);
      _Float16* hp = (_Float16*)h2_sh;
      hp[r * HID + l]      = (_Float16)ha;
      hp[r * HID + l + 64] = (_Float16)hb;
      float pred = fmaf(ha, wla, hb * wlb);
#pragma unroll
      for (int off = 32; off > 0; off >>= 1)
        pred += __shfl_down(pred, off);
      if (l == 0) out[(size_t)(r0 + r) * SEQ + t] = pred + blin;
    }
    // no barrier: next Phase A touches neither g2_sh nor h2_sh; bar1 of t+1
    // (which waves 4/7 reach only after finishing D) orders everything else.
  }
}

extern "C" void kernel_launch(void* const* d_in, const int* in_sizes, int n_in,
                              void* d_out, int out_size, void* d_ws, size_t ws_size,
                              hipStream_t stream) {
  const float* y     = (const float*)d_in[0];
  const float* W_ih1 = (const float*)d_in[1];
  const float* W_hh1 = (const float*)d_in[2];
  const float* b_ih1 = (const float*)d_in[3];
  const float* b_hh1 = (const float*)d_in[4];
  const float* W_ih2 = (const float*)d_in[5];
  const float* W_hh2 = (const float*)d_in[6];
  const float* b_ih2 = (const float*)d_in[7];
  const float* b_hh2 = (const float*)d_in[8];
  const float* W_lin = (const float*)d_in[9];
  const float* b_lin = (const float*)d_in[10];
  float* out = (float*)d_out;

  lstm_persist<<<BATCH / ROWS, TPB, 0, stream>>>(
      y, W_ih1, W_hh1, b_ih1, b_hh1, W_ih2, W_hh2, b_ih2, b_hh2, W_lin, b_lin, out);
}

// Round 7
// 3143.409 us; speedup vs baseline: 1.3843x; 1.0062x over previous
//
#include <hip/hip_runtime.h>

typedef _Float16 half2_t __attribute__((ext_vector_type(2)));
typedef _Float16 half8_t __attribute__((ext_vector_type(8)));

union h8pack { half8_t v; half2_t h2[4]; };

constexpr int BATCH = 512;
constexpr int SEQ   = 1000;
constexpr int HID   = 128;
constexpr int GATES = 4 * HID;   // 512
constexpr int TPB   = 1024;      // 2 threads per gate column (k-split)
constexpr int ROWS  = 2;         // batch rows per block -> 256 blocks = 1/CU
constexpr int KHALF = HID / 2;   // 64 k-elements per thread

#if __has_builtin(__builtin_amdgcn_fdot2)
__device__ __forceinline__ float fdot2(half2_t a, half2_t b, float c) {
  return __builtin_amdgcn_fdot2(a, b, c, false);
}
#else
__device__ __forceinline__ float fdot2(half2_t a, half2_t b, float c) {
  return c + (float)a[0] * (float)b[0] + (float)a[1] * (float)b[1];
}
#endif

__device__ __forceinline__ float fast_sigmoid(float x) {
  x = fminf(fmaxf(x, -30.f), 30.f);
  return __fdividef(1.f, 1.f + __expf(-x));
}
__device__ __forceinline__ float fast_tanh(float x) {
  x = fminf(fmaxf(x, -15.f), 15.f);
  float e = __expf(2.f * x);
  return __fdividef(e - 1.f, e + 1.f);
}

// 4 fdot2 of one half8 against one h8pack
#define DOT8(acc, W, U) { h8pack _w; _w.v = (W);            \
    acc = fdot2(_w.h2[0], (U).h2[0], acc);                  \
    acc = fdot2(_w.h2[1], (U).h2[1], acc);                  \
    acc = fdot2(_w.h2[2], (U).h2[2], acc);                  \
    acc = fdot2(_w.h2[3], (U).h2[3], acc); }

// load 8 consecutive f32 and pack to one half8 register
#define LDW(dst, p, q) { float4 _f0 = (p)[2*(q)]; float4 _f1 = (p)[2*(q)+1]; \
    dst = half8_t{(_Float16)_f0.x, (_Float16)_f0.y, (_Float16)_f0.z,         \
                  (_Float16)_f0.w, (_Float16)_f1.x, (_Float16)_f1.y,         \
                  (_Float16)_f1.z, (_Float16)_f1.w}; }

// w3_lds granule map (64B rotation per kh; conflicts measured inherent-2-way,
// kept because it's harmless and already verified).
#define W3IDX(kq, j) ((kq) * 512 + ((((j) + (((kq) >> 3) << 2))) & 511))

// REGISTER-BUDGET EXPERIMENT LOG (VGPR_Count observed):
//   r0: lb(512,2)            -> 128   r1: lb(1024)        -> 64
//   r2: lb(1024,4)           -> 64    r3/4: wpe(4,4)      -> 64
//   r5: wpe(4,8)             -> 64    r6: wpe+num_vgpr    -> 64
// All consistent with CUDA semantics for launch_bounds arg2 = MIN BLOCKS/CU,
// budget = 512-reg pool / waves-per-SIMD: r0 implied 16 waves/CU -> 128;
// every TPB=1024 variant left the heuristic at 2 blocks/CU (8 waves/SIMD)
// -> 64. lb(1024, 1) pins 1 block/CU -> 4 waves/SIMD -> 128-reg budget,
// fitting the ~90-reg persistent need (64 weight VGPRs + working set).
__global__ __launch_bounds__(TPB, 1)
void lstm_persist(const float* __restrict__ y,
                  const float* __restrict__ W_ih1,
                  const float* __restrict__ W_hh1,
                  const float* __restrict__ b_ih1,
                  const float* __restrict__ b_hh1,
                  const float* __restrict__ W_ih2,
                  const float* __restrict__ W_hh2,
                  const float* __restrict__ b_ih2,
                  const float* __restrict__ b_hh2,
                  const float* __restrict__ W_lin,
                  const float* __restrict__ b_lin,
                  float* __restrict__ out)
{
  const int tid = threadIdx.x;     // 0..1023
  const int j   = tid >> 1;        // gate column 0..511
  const int kh  = tid & 1;         // which half of the k (hidden) dimension
  const int kh8 = kh * 8;
  const int r0  = blockIdx.x * ROWS;

  __shared__ alignas(16) half8_t h1_sh[ROWS][HID / 8];  // h1 state, f16
  __shared__ alignas(16) half8_t h2_sh[ROWS][HID / 8];  // h2 state, f16
  __shared__ float g1_sh[ROWS][GATES];
  __shared__ float g2_sh[ROWS][GATES];
  __shared__ float x_sh[ROWS][SEQ];                     // staged inputs
  __shared__ half8_t w3_lds[16 * 512];                  // W_hh2 f16, 128 KiB

  // ---- stage x for both rows into LDS (coalesced, one-time) ----
  for (int i = tid; i < ROWS * SEQ; i += TPB) {
    const int r  = (i >= SEQ) ? 1 : 0;
    const int tt = i - r * SEQ;
    x_sh[r][tt] = y[(size_t)(r0 + r) * SEQ + tt];
  }
  // ---- zero the h state ----
  if (tid < 64) {
    half8_t z = {};
    if (tid < 32) ((half8_t*)h1_sh)[tid] = z;
    else          ((half8_t*)h2_sh)[tid - 32] = z;
  }
  // ---- stage W_hh2 into LDS (coalesced global reads, one-time) ----
  for (int s = tid; s < 16 * 512; s += TPB) {   // 8 iters
    const int row = s >> 4, kq = s & 15;
    const float4* g = (const float4*)(W_hh2 + (size_t)row * HID + kq * 8);
    float4 f0 = g[0], f1 = g[1];
    w3_lds[W3IDX(kq, row)] =
        half8_t{(_Float16)f0.x, (_Float16)f0.y, (_Float16)f0.z, (_Float16)f0.w,
                (_Float16)f1.x, (_Float16)f1.y, (_Float16)f1.z, (_Float16)f1.w};
  }

  // ---- register weights: 16 NAMED half8 (64 VGPRs), no arrays ----
  half8_t W10, W11, W12, W13, W14, W15, W16, W17;   // W_hh1 row slice
  half8_t W20, W21, W22, W23, W24, W25, W26, W27;   // W_ih2 row slice
  {
    const float4* p1 = (const float4*)(W_hh1 + (size_t)j * HID + kh * KHALF);
    const float4* p2 = (const float4*)(W_ih2 + (size_t)j * HID + kh * KHALF);
    LDW(W10, p1, 0) LDW(W11, p1, 1) LDW(W12, p1, 2) LDW(W13, p1, 3)
    LDW(W14, p1, 4) LDW(W15, p1, 5) LDW(W16, p1, 6) LDW(W17, p1, 7)
    LDW(W20, p2, 0) LDW(W21, p2, 1) LDW(W22, p2, 2) LDW(W23, p2, 3)
    LDW(W24, p2, 4) LDW(W25, p2, 5) LDW(W26, p2, 6) LDW(W27, p2, 7)
  }

  const float wih1  = W_ih1[j];
  const float bias1 = b_ih1[j] + b_hh1[j];
  const float bias2 = b_ih2[j] + b_hh2[j];
  const float wla   = W_lin[tid & 63];
  const float wlb   = W_lin[(tid & 63) + 64];
  const float blin  = b_lin[0];

  float c1v = 0.f;               // layer-1 cell (threads 0..255)
  float c2a = 0.f, c2b = 0.f;    // layer-2 cell (waves 4 and 7, 2 elems each)

  __syncthreads();

  for (int t = 0; t < SEQ; ++t) {
    // ---------- Phase A: layer-1 raw gate partials (all 1024 threads) ----------
    float a0, a1;
    if (kh == 0) {
      a0 = fmaf(x_sh[0][t], wih1, bias1);
      a1 = fmaf(x_sh[1][t], wih1, bias1);
    } else {
      a0 = 0.f; a1 = 0.f;
    }
#define PHA(c, W) { h8pack u0, u1;                   \
      u0.v = h1_sh[0][kh8 + c];                      \
      u1.v = h1_sh[1][kh8 + c];                      \
      DOT8(a0, W, u0); DOT8(a1, W, u1); }
    PHA(0, W10) PHA(1, W11) PHA(2, W12) PHA(3, W13)
    PHA(4, W14) PHA(5, W15) PHA(6, W16) PHA(7, W17)
#undef PHA
    a0 += __shfl_xor(a0, 1);     // pair (2j, 2j+1) lives in the same wave
    a1 += __shfl_xor(a1, 1);
    if (kh == 0) { g1_sh[0][j] = a0; g1_sh[1][j] = a1; }
    __syncthreads();   // bar1: g1 ready; h1 safe to overwrite

    // ---------- Phase B: layer-1 cell update (threads 0..255 = waves 0..3) ----------
    if (tid < ROWS * HID) {
      const int r = tid >> 7, jj = tid & (HID - 1);
      float gi = g1_sh[r][jj];
      float gf = g1_sh[r][jj + HID];
      float gg = g1_sh[r][jj + 2 * HID];
      float go = g1_sh[r][jj + 3 * HID];
      float iv = fast_sigmoid(gi);
      float fv = fast_sigmoid(gf);
      float gv = fast_tanh(gg);
      float ov = fast_sigmoid(go);
      c1v = fmaf(fv, c1v, iv * gv);
      ((_Float16*)h1_sh)[tid] = (_Float16)(ov * fast_tanh(c1v));  // flat == tid
    }
    __syncthreads();   // bar2: h1 ready

    // ---------- Phase C: layer-2 raw gate partials (all 1024 threads) ----------
    float s0, s1;
    if (kh == 0) { s0 = bias2; s1 = bias2; }
    else         { s0 = 0.f;   s1 = 0.f; }
#define PHC1(c, W) { h8pack u0, u1;                  \
      u0.v = h1_sh[0][kh8 + c];                      \
      u1.v = h1_sh[1][kh8 + c];                      \
      DOT8(s0, W, u0); DOT8(s1, W, u1); }
    PHC1(0, W20) PHC1(1, W21) PHC1(2, W22) PHC1(3, W23)
    PHC1(4, W24) PHC1(5, W25) PHC1(6, W26) PHC1(7, W27)
#undef PHC1
#define PHC2(c) { h8pack v0, v1;                     \
      half8_t wr = w3_lds[W3IDX(kh8 + c, j)];        \
      v0.v = h2_sh[0][kh8 + c];                      \
      v1.v = h2_sh[1][kh8 + c];                      \
      DOT8(s0, wr, v0); DOT8(s1, wr, v1); }
    PHC2(0) PHC2(1) PHC2(2) PHC2(3)
    PHC2(4) PHC2(5) PHC2(6) PHC2(7)
#undef PHC2
    s0 += __shfl_xor(s0, 1);
    s1 += __shfl_xor(s1, 1);
    if (kh == 0) { g2_sh[0][j] = s0; g2_sh[1][j] = s1; }
    __syncthreads();   // bar3: g2 ready; h2 safe to overwrite

    // ---------- Phase D: layer-2 cell + output (waves 4 and 7, one row each;
    //            overlaps with the other 14 waves starting Phase A of t+1) ----------
    const int wv = tid >> 6;
    if (wv == 4 || wv == 7) {
      const int r = (wv == 4) ? 0 : 1;
      const int l = tid & 63;              // this thread owns elems l and l+64
      float gia = g2_sh[r][l],       gib = g2_sh[r][l + 64];
      float gfa = g2_sh[r][l + 128], gfb = g2_sh[r][l + 192];
      float gga = g2_sh[r][l + 256], ggb = g2_sh[r][l + 320];
      float goa = g2_sh[r][l + 384], gob = g2_sh[r][l + 448];
      float iva = fast_sigmoid(gia), ivb = fast_sigmoid(gib);
      float fva = fast_sigmoid(gfa), fvb = fast_sigmoid(gfb);
      float gva = fast_tanh(gga),    gvb = fast_tanh(ggb);
      float ova = fast_sigmoid(goa), ovb = fast_sigmoid(gob);
      c2a = fmaf(fva, c2a, iva * gva);
      c2b = fmaf(fvb, c2b, ivb * gvb);
      float ha = ova * fast_tanh(c2a);
      float hb = ovb * fast_tanh(c2b);
      _Float16* hp = (_Float16*)h2_sh;
      hp[r * HID + l]      = (_Float16)ha;
      hp[r * HID + l + 64] = (_Float16)hb;
      float pred = fmaf(ha, wla, hb * wlb);
#pragma unroll
      for (int off = 32; off > 0; off >>= 1)
        pred += __shfl_down(pred, off);
      if (l == 0) out[(size_t)(r0 + r) * SEQ + t] = pred + blin;
    }
    // no barrier: next Phase A touches neither g2_sh nor h2_sh; bar1 of t+1
    // (which waves 4/7 reach only after finishing D) orders everything else.
  }
}

extern "C" void kernel_launch(void* const* d_in, const int* in_sizes, int n_in,
                              void* d_out, int out_size, void* d_ws, size_t ws_size,
                              hipStream_t stream) {
  const float* y     = (const float*)d_in[0];
  const float* W_ih1 = (const float*)d_in[1];
  const float* W_hh1 = (const float*)d_in[2];
  const float* b_ih1 = (const float*)d_in[3];
  const float* b_hh1 = (const float*)d_in[4];
  const float* W_ih2 = (const float*)d_in[5];
  const float* W_hh2 = (const float*)d_in[6];
  const float* b_ih2 = (const float*)d_in[7];
  const float* b_hh2 = (const float*)d_in[8];
  const float* W_lin = (const float*)d_in[9];
  const float* b_lin = (const float*)d_in[10];
  float* out = (float*)d_out;

  lstm_persist<<<BATCH / ROWS, TPB, 0, stream>>>(
      y, W_ih1, W_hh1, b_ih1, b_hh1, W_ih2, W_hh2, b_ih2, b_hh2, W_lin, b_lin, out);
}